// Round 1
// baseline (1940.014 us; speedup 1.0000x reference)
//
#include <hip/hip_runtime.h>
#include <math.h>

#define Bn   4
#define Sn   1024
#define Dn   1024
#define Hn   16
#define DKn  64
#define MRPn 1000

// ---------------------------------------------------------------------------
// C[M,N] = A[M,K] @ W[N,K]^T + bias[N]    (both operands K-contiguous)
// 128x128 tile, BK=16, 256 threads, 8x8 micro-tile.
// ---------------------------------------------------------------------------
__global__ __launch_bounds__(256) void gemm_bt_bias(
    const float* __restrict__ A, const float* __restrict__ W,
    const float* __restrict__ bias, float* __restrict__ C,
    int M, int N, int K)
{
    __shared__ float As[16][132];
    __shared__ float Bs[16][132];
    const int tid = threadIdx.x;
    const int tx = tid & 15, ty = tid >> 4;
    const int m0 = blockIdx.y * 128, n0 = blockIdx.x * 128;

    float acc[8][8];
#pragma unroll
    for (int i = 0; i < 8; ++i)
#pragma unroll
        for (int j = 0; j < 8; ++j) acc[i][j] = 0.f;

    for (int kb = 0; kb < K; kb += 16) {
#pragma unroll
        for (int t = 0; t < 2; ++t) {
            int idx = tid + t * 256;          // 0..511
            int m   = idx >> 2;               // 0..127
            int k4  = (idx & 3) << 2;         // 0,4,8,12
            float4 a4 = *(const float4*)(A + (size_t)(m0 + m) * K + kb + k4);
            As[k4+0][m] = a4.x; As[k4+1][m] = a4.y;
            As[k4+2][m] = a4.z; As[k4+3][m] = a4.w;
            float4 b4 = *(const float4*)(W + (size_t)(n0 + m) * K + kb + k4);
            Bs[k4+0][m] = b4.x; Bs[k4+1][m] = b4.y;
            Bs[k4+2][m] = b4.z; Bs[k4+3][m] = b4.w;
        }
        __syncthreads();
#pragma unroll
        for (int kk = 0; kk < 16; ++kk) {
            float4 a01 = *(const float4*)&As[kk][ty * 8];
            float4 a23 = *(const float4*)&As[kk][ty * 8 + 4];
            float4 b01 = *(const float4*)&Bs[kk][tx * 8];
            float4 b23 = *(const float4*)&Bs[kk][tx * 8 + 4];
            float a[8] = {a01.x, a01.y, a01.z, a01.w, a23.x, a23.y, a23.z, a23.w};
            float b[8] = {b01.x, b01.y, b01.z, b01.w, b23.x, b23.y, b23.z, b23.w};
#pragma unroll
            for (int i = 0; i < 8; ++i)
#pragma unroll
                for (int j = 0; j < 8; ++j)
                    acc[i][j] = fmaf(a[i], b[j], acc[i][j]);
        }
        __syncthreads();
    }

#pragma unroll
    for (int i = 0; i < 8; ++i) {
        int m = m0 + ty * 8 + i;
#pragma unroll
        for (int j4 = 0; j4 < 2; ++j4) {
            int n = n0 + tx * 8 + j4 * 4;
            float4 o;
            o.x = acc[i][j4*4+0] + bias[n+0];
            o.y = acc[i][j4*4+1] + bias[n+1];
            o.z = acc[i][j4*4+2] + bias[n+2];
            o.w = acc[i][j4*4+3] + bias[n+3];
            *(float4*)(C + (size_t)m * N + n) = o;
        }
    }
}

// ---------------------------------------------------------------------------
// logits[bh,q,k] = sum_d Q[b,h,q,d]*K[b,h,k,d] + sum_d Q[b,h,q,d]*embK[clip(k-q)+MRP][d]
// Block: one 64q x 64k tile of one (b,h), processed as two 64x32 halves.
// Q/K stored [s][d] with +1 pad; Es holds the 95 distinct emb rows of the half.
// ---------------------------------------------------------------------------
__global__ __launch_bounds__(256) void logits_kernel(
    const float* __restrict__ Qp, const float* __restrict__ Kp,
    const float* __restrict__ embK, float* __restrict__ L)
{
    __shared__ float Qs[64][65];
    __shared__ float Ks[32][65];
    __shared__ float Es[95][65];
    const int tid = threadIdx.x;
    const int tx = tid & 15, ty = tid >> 4;
    const int bh = blockIdx.z;
    const int b = bh >> 4, h = bh & 15;
    const int q0 = blockIdx.y * 64;

    for (int i = tid; i < 64 * 64; i += 256) {
        int r = i >> 6, d = i & 63;
        Qs[r][d] = Qp[(size_t)(b * Sn + q0 + r) * Dn + h * DKn + d];
    }

    for (int half = 0; half < 2; ++half) {
        const int k0 = blockIdx.x * 64 + half * 32;
        __syncthreads();   // Qs ready (half 0) / previous compute done (half 1)
        for (int i = tid; i < 32 * 64; i += 256) {
            int r = i >> 6, d = i & 63;
            Ks[r][d] = Kp[(size_t)(b * Sn + k0 + r) * Dn + h * DKn + d];
        }
        for (int i = tid; i < 95 * 64; i += 256) {
            int r = i >> 6, d = i & 63;
            int diff = k0 - q0 - 63 + r;
            diff = min(max(diff, -MRPn), MRPn);
            Es[r][d] = embK[(size_t)(diff + MRPn) * DKn + d];
        }
        __syncthreads();

        float acc[4][2];
#pragma unroll
        for (int i = 0; i < 4; ++i) { acc[i][0] = 0.f; acc[i][1] = 0.f; }
        const int c0 = 2 * tx - 4 * ty + 63;   // rel row for (qi=4ty, ki=2tx)

#pragma unroll 4
        for (int d = 0; d < 64; ++d) {
            float q[4], k[2], e[5];
#pragma unroll
            for (int i = 0; i < 4; ++i) q[i] = Qs[4 * ty + i][d];
#pragma unroll
            for (int j = 0; j < 2; ++j) k[j] = Ks[2 * tx + j][d];
#pragma unroll
            for (int t = 0; t < 5; ++t) e[t] = Es[c0 - 3 + t][d];
#pragma unroll
            for (int i = 0; i < 4; ++i)
#pragma unroll
                for (int j = 0; j < 2; ++j)
                    acc[i][j] = fmaf(q[i], k[j] + e[j - i + 3], acc[i][j]);
        }

#pragma unroll
        for (int i = 0; i < 4; ++i) {
            int qq = q0 + 4 * ty + i;
#pragma unroll
            for (int j = 0; j < 2; ++j) {
                int kg = k0 + 2 * tx + j;
                L[((size_t)bh * Sn + qq) * Sn + kg] = acc[i][j];
            }
        }
    }
}

// ---------------------------------------------------------------------------
// In-place row softmax over last dim (1024). One block (256 thr) per row.
// ---------------------------------------------------------------------------
__global__ __launch_bounds__(256) void softmax_kernel(float* __restrict__ Wt)
{
    __shared__ float red[4];
    const int tid = threadIdx.x;
    float* p = Wt + (size_t)blockIdx.x * Sn;
    float4 v = ((const float4*)p)[tid];

    float m = fmaxf(fmaxf(v.x, v.y), fmaxf(v.z, v.w));
#pragma unroll
    for (int o = 32; o > 0; o >>= 1) m = fmaxf(m, __shfl_down(m, o, 64));
    if ((tid & 63) == 0) red[tid >> 6] = m;
    __syncthreads();
    m = fmaxf(fmaxf(red[0], red[1]), fmaxf(red[2], red[3]));
    __syncthreads();

    float4 e;
    e.x = expf(v.x - m); e.y = expf(v.y - m);
    e.z = expf(v.z - m); e.w = expf(v.w - m);
    float s = e.x + e.y + e.z + e.w;
#pragma unroll
    for (int o = 32; o > 0; o >>= 1) s += __shfl_down(s, o, 64);
    if ((tid & 63) == 0) red[tid >> 6] = s;
    __syncthreads();
    s = red[0] + red[1] + red[2] + red[3];

    float inv = 1.0f / s;
    e.x *= inv; e.y *= inv; e.z *= inv; e.w *= inv;
    ((float4*)p)[tid] = e;
}

// ---------------------------------------------------------------------------
// X[b,h,q,d] = sum_k W[bh,q,k] * ( V[b,h,k,d] + embV[clip(k-q)+MRP][d] )
// Block: 64 q-rows of one (b,h); k staged by 32.
// ---------------------------------------------------------------------------
__global__ __launch_bounds__(256) void av_kernel(
    const float* __restrict__ Wt, const float* __restrict__ Vp,
    const float* __restrict__ embV, float* __restrict__ X)
{
    __shared__ float Ws[64][33];
    __shared__ float Vs[32][65];
    __shared__ float Es[95][65];
    const int tid = threadIdx.x;
    const int tx = tid & 15, ty = tid >> 4;
    const int bh = blockIdx.y;
    const int b = bh >> 4, h = bh & 15;
    const int q0 = blockIdx.x * 64;

    float acc[4][4];
#pragma unroll
    for (int i = 0; i < 4; ++i)
#pragma unroll
        for (int j = 0; j < 4; ++j) acc[i][j] = 0.f;

    for (int k0 = 0; k0 < Sn; k0 += 32) {
        __syncthreads();
        for (int i = tid; i < 64 * 32; i += 256) {
            int r = i >> 5, c = i & 31;
            Ws[r][c] = Wt[((size_t)bh * Sn + q0 + r) * Sn + k0 + c];
        }
        for (int i = tid; i < 32 * 64; i += 256) {
            int r = i >> 6, d = i & 63;
            Vs[r][d] = Vp[(size_t)(b * Sn + k0 + r) * Dn + h * DKn + d];
        }
        for (int i = tid; i < 95 * 64; i += 256) {
            int r = i >> 6, d = i & 63;
            int diff = k0 - q0 - 63 + r;
            diff = min(max(diff, -MRPn), MRPn);
            Es[r][d] = embV[(size_t)(diff + MRPn) * DKn + d];
        }
        __syncthreads();

#pragma unroll 4
        for (int kk = 0; kk < 32; ++kk) {
            float w[4], v[4];
#pragma unroll
            for (int i = 0; i < 4; ++i) w[i] = Ws[4 * ty + i][kk];
#pragma unroll
            for (int j = 0; j < 4; ++j) v[j] = Vs[kk][4 * tx + j];
#pragma unroll
            for (int i = 0; i < 4; ++i) {
                int ri = kk - 4 * ty - i + 63;   // in [0,94]
#pragma unroll
                for (int j = 0; j < 4; ++j)
                    acc[i][j] = fmaf(w[i], v[j] + Es[ri][4 * tx + j], acc[i][j]);
            }
        }
    }

#pragma unroll
    for (int i = 0; i < 4; ++i) {
        int q = q0 + 4 * ty + i;
#pragma unroll
        for (int j = 0; j < 4; ++j)
            X[(size_t)(b * Sn + q) * Dn + h * DKn + 4 * tx + j] = acc[i][j];
    }
}

// ---------------------------------------------------------------------------
extern "C" void kernel_launch(void* const* d_in, const int* in_sizes, int n_in,
                              void* d_out, int out_size, void* d_ws, size_t ws_size,
                              hipStream_t stream)
{
    const float* query = (const float*)d_in[0];
    const float* key   = (const float*)d_in[1];
    const float* value = (const float*)d_in[2];
    const float* Wq    = (const float*)d_in[3];
    const float* bq    = (const float*)d_in[4];
    const float* Wk    = (const float*)d_in[5];
    const float* bk    = (const float*)d_in[6];
    const float* Wv    = (const float*)d_in[7];
    const float* bv    = (const float*)d_in[8];
    const float* Wo    = (const float*)d_in[9];
    const float* bo    = (const float*)d_in[10];
    const float* embK  = (const float*)d_in[11];
    const float* embV  = (const float*)d_in[12];

    const size_t NTOK = (size_t)Bn * Sn;          // 4096
    const size_t PROJ = NTOK * Dn;                // 4,194,304 floats

    float* ws  = (float*)d_ws;
    float* Q   = ws;                              // [4096,1024]
    float* Kp  = ws + PROJ;
    float* Vp  = ws + 2 * PROJ;
    float* X   = ws;                              // reuse Q slot (Q dead after logits)

    float* outp = (float*)d_out;                  // [B,S,D]
    float* Wt   = outp + PROJ;                    // weights [B,H,S,S]

    dim3 gemmGrid(Dn / 128, (int)(NTOK / 128));   // (8, 32)

    gemm_bt_bias<<<gemmGrid, 256, 0, stream>>>(query, Wq, bq, Q,  (int)NTOK, Dn, Dn);
    gemm_bt_bias<<<gemmGrid, 256, 0, stream>>>(key,   Wk, bk, Kp, (int)NTOK, Dn, Dn);
    gemm_bt_bias<<<gemmGrid, 256, 0, stream>>>(value, Wv, bv, Vp, (int)NTOK, Dn, Dn);

    logits_kernel<<<dim3(Sn / 64, Sn / 64, Bn * Hn), 256, 0, stream>>>(Q, Kp, embK, Wt);

    softmax_kernel<<<Bn * Hn * Sn, 256, 0, stream>>>(Wt);

    av_kernel<<<dim3(Sn / 64, Bn * Hn), 256, 0, stream>>>(Wt, Vp, embV, X);

    gemm_bt_bias<<<gemmGrid, 256, 0, stream>>>(X, Wo, bo, outp, (int)NTOK, Dn, Dn);
}

// Round 2
// 1765.089 us; speedup vs baseline: 1.0991x; 1.0991x over previous
//
#include <hip/hip_runtime.h>
#include <math.h>

#define Bn   4
#define Sn   1024
#define Dn   1024
#define Hn   16
#define DKn  64
#define MRPn 1000

typedef __attribute__((ext_vector_type(8))) short short8;
typedef __attribute__((ext_vector_type(4))) float f32x4;

static __device__ __forceinline__ unsigned short f2bf(float f) {
    unsigned u = __float_as_uint(f);
    u += 0x7FFF + ((u >> 16) & 1);          // RNE
    return (unsigned short)(u >> 16);
}

// ---------------------------------------------------------------------------
// fp32 -> bf16 cast, 4 elems/thread. n must be multiple of 4 (true here).
// ---------------------------------------------------------------------------
__global__ __launch_bounds__(256) void cast_f32_bf16(
    const float* __restrict__ s, unsigned short* __restrict__ d, int n)
{
    int i = (blockIdx.x * 256 + threadIdx.x) * 4;
    if (i >= n) return;
    float4 v = *(const float4*)(s + i);
    ushort4 o;
    o.x = f2bf(v.x); o.y = f2bf(v.y); o.z = f2bf(v.z); o.w = f2bf(v.w);
    *(ushort4*)(d + i) = o;
}

// ---------------------------------------------------------------------------
// C[M,N] = A[M,K](bf16) @ W[N,K](bf16)^T + bias[N], fp32 out.
// 128x128 tile, BK=32, 4 waves, each wave 64x64 via 4x4 grid of 16x16x32 MFMA.
// A/B frag: 8 contiguous k at row lane&15, k-offset quad*8 (guide §3, m89/m120).
// D: row = quad*4+reg, col = lane&15 (m89-verified).
// M,N %128==0, K %32==0 assumed.
// ---------------------------------------------------------------------------
#define LP 40   // LDS row pitch in bf16 elems (80 B, 16B-aligned, conflict-spread)
__global__ __launch_bounds__(256) void gemm_bf16_mfma(
    const unsigned short* __restrict__ A, const unsigned short* __restrict__ W,
    const float* __restrict__ bias, float* __restrict__ C,
    int M, int N, int K)
{
    __shared__ unsigned short As[128 * LP];
    __shared__ unsigned short Bs[128 * LP];
    const int tid  = threadIdx.x;
    const int lane = tid & 63;
    const int wave = tid >> 6;
    const int m0 = blockIdx.y * 128, n0 = blockIdx.x * 128;
    const int wm = (wave & 1) * 64, wn = (wave >> 1) * 64;
    const int fr   = lane & 15;
    const int quad = lane >> 4;

    f32x4 acc[4][4];
#pragma unroll
    for (int i = 0; i < 4; ++i)
#pragma unroll
        for (int j = 0; j < 4; ++j) acc[i][j] = (f32x4){0.f, 0.f, 0.f, 0.f};

    const int srow   = tid >> 2;        // 0..63 (and +64 in pass 2)
    const int schunk = (tid & 3) * 8;   // k-element offset 0,8,16,24

    for (int kb = 0; kb < K; kb += 32) {
        const unsigned short* ga = A + (size_t)(m0 + srow) * K + kb + schunk;
        const unsigned short* gb = W + (size_t)(n0 + srow) * K + kb + schunk;
        short8 a0 = *(const short8*)ga;
        short8 a1 = *(const short8*)(ga + (size_t)64 * K);
        short8 b0 = *(const short8*)gb;
        short8 b1 = *(const short8*)(gb + (size_t)64 * K);
        __syncthreads();                 // previous iter's frag reads done
        *(short8*)&As[srow * LP + schunk]        = a0;
        *(short8*)&As[(srow + 64) * LP + schunk] = a1;
        *(short8*)&Bs[srow * LP + schunk]        = b0;
        *(short8*)&Bs[(srow + 64) * LP + schunk] = b1;
        __syncthreads();

        short8 af[4], bf[4];
#pragma unroll
        for (int mi = 0; mi < 4; ++mi)
            af[mi] = *(const short8*)&As[(wm + 16 * mi + fr) * LP + quad * 8];
#pragma unroll
        for (int ni = 0; ni < 4; ++ni)
            bf[ni] = *(const short8*)&Bs[(wn + 16 * ni + fr) * LP + quad * 8];
#pragma unroll
        for (int mi = 0; mi < 4; ++mi)
#pragma unroll
            for (int ni = 0; ni < 4; ++ni)
                acc[mi][ni] = __builtin_amdgcn_mfma_f32_16x16x32_bf16(
                    af[mi], bf[ni], acc[mi][ni], 0, 0, 0);
    }

#pragma unroll
    for (int ni = 0; ni < 4; ++ni) {
        int cc = n0 + wn + 16 * ni + fr;
        float bv = bias[cc];
#pragma unroll
        for (int mi = 0; mi < 4; ++mi) {
            int rbase = m0 + wm + 16 * mi + quad * 4;
#pragma unroll
            for (int r = 0; r < 4; ++r)
                C[(size_t)(rbase + r) * N + cc] = acc[mi][ni][r] + bv;
        }
    }
}

// ---------------------------------------------------------------------------
// logits[bh,q,k] = Q[q,:].K[k,:] + Q[q,:].embK[clip(k-q)+MRP,:]
// Remapped micro-tile: q = ty+16i, k = tx+16j -> all LDS reads broadcast or
// 2-way (free). e-row = tx-ty+15+16t, t=j-i+3 (5 shared rows per thread).
// ---------------------------------------------------------------------------
__global__ __launch_bounds__(256) void logits_kernel(
    const float* __restrict__ Qp, const float* __restrict__ Kp,
    const float* __restrict__ embK, float* __restrict__ L)
{
    __shared__ float Qs[64][65];
    __shared__ float Ks[32][65];
    __shared__ float Es[95][65];
    const int tid = threadIdx.x;
    const int tx = tid & 15, ty = tid >> 4;
    const int bh = blockIdx.z;
    const int b = bh >> 4, h = bh & 15;
    const int q0 = blockIdx.y * 64;

    for (int i = tid; i < 64 * 64; i += 256) {
        int r = i >> 6, d = i & 63;
        Qs[r][d] = Qp[(size_t)(b * Sn + q0 + r) * Dn + h * DKn + d];
    }

    for (int half = 0; half < 2; ++half) {
        const int k0 = blockIdx.x * 64 + half * 32;
        __syncthreads();   // Qs ready / previous half's compute done
        for (int i = tid; i < 32 * 64; i += 256) {
            int r = i >> 6, d = i & 63;
            Ks[r][d] = Kp[(size_t)(b * Sn + k0 + r) * Dn + h * DKn + d];
        }
        for (int i = tid; i < 95 * 64; i += 256) {
            int r = i >> 6, d = i & 63;
            int diff = k0 - q0 - 63 + r;
            diff = min(max(diff, -MRPn), MRPn);
            Es[r][d] = embK[(size_t)(diff + MRPn) * DKn + d];
        }
        __syncthreads();

        float acc[4][2];
#pragma unroll
        for (int i = 0; i < 4; ++i) { acc[i][0] = 0.f; acc[i][1] = 0.f; }
        const int erow = tx - ty + 15;   // + 16*t

#pragma unroll 4
        for (int d = 0; d < 64; ++d) {
            float q[4], k[2], e[5];
#pragma unroll
            for (int i = 0; i < 4; ++i) q[i] = Qs[ty + 16 * i][d];
#pragma unroll
            for (int j = 0; j < 2; ++j) k[j] = Ks[tx + 16 * j][d];
#pragma unroll
            for (int t = 0; t < 5; ++t) e[t] = Es[erow + 16 * t][d];
#pragma unroll
            for (int i = 0; i < 4; ++i)
#pragma unroll
                for (int j = 0; j < 2; ++j)
                    acc[i][j] = fmaf(q[i], k[j] + e[j - i + 3], acc[i][j]);
        }

#pragma unroll
        for (int i = 0; i < 4; ++i) {
            int qq = q0 + ty + 16 * i;
#pragma unroll
            for (int j = 0; j < 2; ++j)
                L[((size_t)bh * Sn + qq) * Sn + k0 + tx + 16 * j] = acc[i][j];
        }
    }
}

// ---------------------------------------------------------------------------
// In-place row softmax over last dim (1024). One block (256 thr) per row.
// ---------------------------------------------------------------------------
__global__ __launch_bounds__(256) void softmax_kernel(float* __restrict__ Wt)
{
    __shared__ float red[4];
    const int tid = threadIdx.x;
    float* p = Wt + (size_t)blockIdx.x * Sn;
    float4 v = ((const float4*)p)[tid];

    float m = fmaxf(fmaxf(v.x, v.y), fmaxf(v.z, v.w));
#pragma unroll
    for (int o = 32; o > 0; o >>= 1) m = fmaxf(m, __shfl_down(m, o, 64));
    if ((tid & 63) == 0) red[tid >> 6] = m;
    __syncthreads();
    m = fmaxf(fmaxf(red[0], red[1]), fmaxf(red[2], red[3]));
    __syncthreads();

    float4 e;
    e.x = expf(v.x - m); e.y = expf(v.y - m);
    e.z = expf(v.z - m); e.w = expf(v.w - m);
    float s = e.x + e.y + e.z + e.w;
#pragma unroll
    for (int o = 32; o > 0; o >>= 1) s += __shfl_down(s, o, 64);
    if ((tid & 63) == 0) red[tid >> 6] = s;
    __syncthreads();
    s = red[0] + red[1] + red[2] + red[3];

    float inv = 1.0f / s;
    e.x *= inv; e.y *= inv; e.z *= inv; e.w *= inv;
    ((float4*)p)[tid] = e;
}

// ---------------------------------------------------------------------------
// X[b,q,h*64+d] = sum_k W[bh,q,k] * (V[k,d] + embV[clip(k-q)+MRP][d])
// Remapped: q = ty+16i, d = 4tx+j. Es bank = (-ty+4tx+c)%32 -> exact 2-way
// (free, m136). Output written directly as bf16 for the Wo GEMM.
// ---------------------------------------------------------------------------
__global__ __launch_bounds__(256) void av_kernel(
    const float* __restrict__ Wt, const float* __restrict__ Vp,
    const float* __restrict__ embV, unsigned short* __restrict__ Xbf)
{
    __shared__ float Ws[64][33];
    __shared__ float Vs[32][65];
    __shared__ float Es[95][65];
    const int tid = threadIdx.x;
    const int tx = tid & 15, ty = tid >> 4;
    const int bh = blockIdx.y;
    const int b = bh >> 4, h = bh & 15;
    const int q0 = blockIdx.x * 64;

    float acc[4][4];
#pragma unroll
    for (int i = 0; i < 4; ++i)
#pragma unroll
        for (int j = 0; j < 4; ++j) acc[i][j] = 0.f;

    for (int k0 = 0; k0 < Sn; k0 += 32) {
        __syncthreads();
        for (int i = tid; i < 64 * 32; i += 256) {
            int r = i >> 5, c = i & 31;
            Ws[r][c] = Wt[((size_t)bh * Sn + q0 + r) * Sn + k0 + c];
        }
        for (int i = tid; i < 32 * 64; i += 256) {
            int r = i >> 6, d = i & 63;
            Vs[r][d] = Vp[(size_t)(b * Sn + k0 + r) * Dn + h * DKn + d];
        }
        for (int i = tid; i < 95 * 64; i += 256) {
            int r = i >> 6, d = i & 63;
            int diff = k0 - q0 - 63 + r;
            diff = min(max(diff, -MRPn), MRPn);
            Es[r][d] = embV[(size_t)(diff + MRPn) * DKn + d];
        }
        __syncthreads();

#pragma unroll 2
        for (int kk = 0; kk < 32; ++kk) {
            float w[4], v[4];
#pragma unroll
            for (int i = 0; i < 4; ++i) w[i] = Ws[ty + 16 * i][kk];
#pragma unroll
            for (int j = 0; j < 4; ++j) v[j] = Vs[kk][4 * tx + j];
#pragma unroll
            for (int i = 0; i < 4; ++i) {
                int ri = kk - ty - 16 * i + 63;   // in [0,94]
#pragma unroll
                for (int j = 0; j < 4; ++j)
                    acc[i][j] = fmaf(w[i], v[j] + Es[ri][4 * tx + j], acc[i][j]);
            }
        }
    }

#pragma unroll
    for (int i = 0; i < 4; ++i) {
        int q = q0 + ty + 16 * i;
        ushort4 o;
        o.x = f2bf(acc[i][0]); o.y = f2bf(acc[i][1]);
        o.z = f2bf(acc[i][2]); o.w = f2bf(acc[i][3]);
        *(ushort4*)(Xbf + (size_t)(b * Sn + q) * Dn + h * DKn + 4 * tx) = o;
    }
}

// ---------------------------------------------------------------------------
extern "C" void kernel_launch(void* const* d_in, const int* in_sizes, int n_in,
                              void* d_out, int out_size, void* d_ws, size_t ws_size,
                              hipStream_t stream)
{
    const float* query = (const float*)d_in[0];
    const float* key   = (const float*)d_in[1];
    const float* value = (const float*)d_in[2];
    const float* Wq    = (const float*)d_in[3];
    const float* bq    = (const float*)d_in[4];
    const float* Wk    = (const float*)d_in[5];
    const float* bk    = (const float*)d_in[6];
    const float* Wv    = (const float*)d_in[7];
    const float* bv    = (const float*)d_in[8];
    const float* Wo    = (const float*)d_in[9];
    const float* bo    = (const float*)d_in[10];
    const float* embK  = (const float*)d_in[11];
    const float* embV  = (const float*)d_in[12];

    const size_t NTOK = (size_t)Bn * Sn;          // 4096
    const size_t PROJ = NTOK * Dn;                // 4,194,304
    const size_t WSZ  = (size_t)Dn * Dn;          // 1,048,576

    float* ws  = (float*)d_ws;
    float* Q   = ws;                              // fp32 [4096,1024]
    float* Kp  = ws + PROJ;
    float* Vp  = ws + 2 * PROJ;
    unsigned short* Abf = (unsigned short*)(ws + 3 * PROJ);  // bf16 [4096,1024], reused 4x
    unsigned short* Wqb = Abf + PROJ;
    unsigned short* Wkb = Wqb + WSZ;
    unsigned short* Wvb = Wkb + WSZ;
    unsigned short* Wob = Wvb + WSZ;

    float* outp = (float*)d_out;                  // [B,S,D]
    float* Wt   = outp + PROJ;                    // weights [B,H,S,S]

    const int CAST_W_GRID = (int)(WSZ / 4 / 256);
    const int CAST_A_GRID = (int)(PROJ / 4 / 256);
    dim3 gemmGrid(Dn / 128, (int)(NTOK / 128));   // (8, 32)

    cast_f32_bf16<<<CAST_W_GRID, 256, 0, stream>>>(Wq, Wqb, (int)WSZ);
    cast_f32_bf16<<<CAST_W_GRID, 256, 0, stream>>>(Wk, Wkb, (int)WSZ);
    cast_f32_bf16<<<CAST_W_GRID, 256, 0, stream>>>(Wv, Wvb, (int)WSZ);
    cast_f32_bf16<<<CAST_W_GRID, 256, 0, stream>>>(Wo, Wob, (int)WSZ);

    cast_f32_bf16<<<CAST_A_GRID, 256, 0, stream>>>(query, Abf, (int)PROJ);
    gemm_bf16_mfma<<<gemmGrid, 256, 0, stream>>>(Abf, Wqb, bq, Q,  (int)NTOK, Dn, Dn);
    cast_f32_bf16<<<CAST_A_GRID, 256, 0, stream>>>(key, Abf, (int)PROJ);
    gemm_bf16_mfma<<<gemmGrid, 256, 0, stream>>>(Abf, Wkb, bk, Kp, (int)NTOK, Dn, Dn);
    cast_f32_bf16<<<CAST_A_GRID, 256, 0, stream>>>(value, Abf, (int)PROJ);
    gemm_bf16_mfma<<<gemmGrid, 256, 0, stream>>>(Abf, Wvb, bv, Vp, (int)NTOK, Dn, Dn);

    logits_kernel<<<dim3(Sn / 64, Sn / 64, Bn * Hn), 256, 0, stream>>>(Q, Kp, embK, Wt);

    softmax_kernel<<<Bn * Hn * Sn, 256, 0, stream>>>(Wt);

    av_kernel<<<dim3(Sn / 64, Bn * Hn), 256, 0, stream>>>(Wt, Vp, embV, Abf);

    gemm_bf16_mfma<<<gemmGrid, 256, 0, stream>>>(Abf, Wob, bo, outp, (int)NTOK, Dn, Dn);
}